// Round 6
// baseline (677.999 us; speedup 1.0000x reference)
//
#include <hip/hip_runtime.h>
#include <hip/hip_cooperative_groups.h>

// ---------------------------------------------------------------------------
// Single cooperative kernel, 3 phases separated by grid.sync():
//  P1 (err): 5504 virtual blocks (4096-px chunks) grid-strided over 1024 real
//    blocks. blocks/patch: s0=32,s1=8,s2=2,s3=1; bases {0,4096,5120,5376}.
//    Partials SoA chunk-major: id = base_i + chunk*128 + patch (A,N,Q planes).
//  P2 (finalize): block 0 reduces partials (explicit nch {32,8,2,1}),
//    computes argmin mask (first-min tie-break) + loss -> out[0].
//  P3 (write): 4 px/thread groups, 16 grid-strided iterations; 16B-aligned
//    f32x4 nontemporal stores (d_out+1 base => groups at i==3 mod 4 aligned).
// __threadfence() (agent scope -> L2 wb/inv) around grid.sync() for cross-XCD
// visibility of partials and mask.
// ---------------------------------------------------------------------------

typedef float f32x4 __attribute__((ext_vector_type(4)));
namespace cg = cooperative_groups;

__device__ __forceinline__ void px_val(
    int i,
    const float* __restrict__ pre0, const float* __restrict__ gt0,
    const float* __restrict__ pre1, const float* __restrict__ gt1,
    const float* __restrict__ pre2, const float* __restrict__ gt2,
    const float* __restrict__ pre3, const float* __restrict__ gt3,
    const int* __restrict__ mask, float& ov, float& lv)
{
    const int b = i >> 20;
    const int y = (i >> 10) & 1023;
    const int x = i & 1023;
    const int pi = y >> 9, pj = x >> 8;
    const int r  = y & 511, c = x & 255;
    const int m  = mask[(b << 3) + (pi << 2) + pj];
    const int kh = 512 >> m, kw = 256 >> m;
    const unsigned rr = (unsigned)(r - ((512 - kh) >> 1));
    const unsigned cc = (unsigned)(c - ((256 - kw) >> 1));
    if (rr < (unsigned)kh && cc < (unsigned)kw) {
        const int wdim = 1024 >> m;
        const float* __restrict__ pre = (m == 0) ? pre0 : (m == 1) ? pre1 : (m == 2) ? pre2 : pre3;
        const float* __restrict__ gt  = (m == 0) ? gt0  : (m == 1) ? gt1  : (m == 2) ? gt2  : gt3;
        const int idx = b * wdim * wdim + (pi * kh + (int)rr) * wdim + (pj * kw + (int)cc);
        ov = pre[idx] * (1.0f / 200.0f);
        lv = gt[idx];
    } else {
        ov = 0.001f;       // 0.2 / WEIGHT
        lv = 0.001f;
    }
}

__global__ __launch_bounds__(256, 4) void k_fused(
    const float* __restrict__ pre0, const float* __restrict__ gt0,
    const float* __restrict__ pre1, const float* __restrict__ gt1,
    const float* __restrict__ pre2, const float* __restrict__ gt2,
    const float* __restrict__ pre3, const float* __restrict__ gt3,
    float* __restrict__ pA, float* __restrict__ pN, float* __restrict__ pQ,
    int* __restrict__ mask, float* __restrict__ out)
{
    cg::grid_group grid = cg::this_grid();
    const int t = threadIdx.x;

    __shared__ float wA[4], wN[4], wQ[4];
    __shared__ float A[512], N[512], Q[512];   // [i*128 + p] (phase 2)
    __shared__ float qsel[128];
    __shared__ int   msel[128];

    // ---------------- Phase 1: per-chunk error partials ----------------
    for (int vb = blockIdx.x; vb < 5504; vb += 1024) {
        int scale, patch, chunk, oidx;
        const float* __restrict__ pre;
        const float* __restrict__ gt;
        if (vb < 4096)      { scale = 0; patch = vb >> 5; chunk = vb & 31;
                              oidx = chunk * 128 + patch;          pre = pre0; gt = gt0; }
        else if (vb < 5120) { scale = 1; int r = vb - 4096; patch = r >> 3; chunk = r & 7;
                              oidx = 4096 + chunk * 128 + patch;   pre = pre1; gt = gt1; }
        else if (vb < 5376) { scale = 2; int r = vb - 5120; patch = r >> 1; chunk = r & 1;
                              oidx = 5120 + chunk * 128 + patch;   pre = pre2; gt = gt2; }
        else                { scale = 3; patch = vb - 5376; chunk = 0;
                              oidx = 5376 + patch;                 pre = pre3; gt = gt3; }

        const int b  = patch >> 3;
        const int l  = patch & 7;
        const int pi = l >> 2, pj = l & 3;
        const int kwshift = 8 - scale;            // kw = 256>>scale
        const int kw   = 1 << kwshift;
        const int kh   = 512 >> scale;
        const int wdim = 1024 >> scale;
        const int patch_px = 131072 >> (2 * scale);
        const int imgbase  = b * wdim * wdim;
        const int base_row = pi * kh;
        const int base_col = pj * kw;

        float sumabs = 0.f, npos = 0.f, sq = 0.f;
#pragma unroll
        for (int s = 0; s < 4; ++s) {
            const int slot = t + s * 256;                 // 0..1023 f32x4 slots
            const int px   = chunk * 4096 + slot * 4;
            if (px < patch_px) {                          // only scale-3 trims
                const int row  = px >> kwshift;
                const int col  = px & (kw - 1);
                const int idx  = imgbase + (base_row + row) * wdim + base_col + col;
                const f32x4 p = *reinterpret_cast<const f32x4*>(pre + idx);
                const f32x4 g = *reinterpret_cast<const f32x4*>(gt + idx);
#pragma unroll
                for (int k = 0; k < 4; ++k) {
                    const float gs = g[k] * 200.0f;       // gts = gt * WEIGHT
                    const float d  = gs - p[k];
                    sq += d * d;
                    if (g[k] > 0.0f) { sumabs += fabsf(d); npos += 1.0f; }
                }
            }
        }

        for (int off = 32; off > 0; off >>= 1) {
            sumabs += __shfl_down(sumabs, off);
            npos   += __shfl_down(npos,   off);
            sq     += __shfl_down(sq,     off);
        }
        const int w = t >> 6;
        if ((t & 63) == 0) { wA[w] = sumabs; wN[w] = npos; wQ[w] = sq; }
        __syncthreads();
        if (t == 0) {
            pA[oidx] = (wA[0] + wA[1]) + (wA[2] + wA[3]);
            pN[oidx] = (wN[0] + wN[1]) + (wN[2] + wN[3]);
            pQ[oidx] = (wQ[0] + wQ[1]) + (wQ[2] + wQ[3]);
        }
        __syncthreads();   // protect wA/wN/wQ reuse next iteration
    }

    __threadfence();
    grid.sync();

    // ---------------- Phase 2: finalize (block 0 only) ----------------
    if (blockIdx.x == 0) {
        const int p  = t & 127;
        const int i0 = (t < 128) ? 0 : 1;
#pragma unroll
        for (int k = 0; k < 2; ++k) {
            const int i    = i0 + 2 * k;
            const int base = (i == 0) ? 0 : (i == 1) ? 4096 : (i == 2) ? 5120 : 5376;
            const int nch  = (i == 0) ? 32 : (i == 1) ? 8 : (i == 2) ? 2 : 1;  // EXPLICIT
            float a = 0.f, n = 0.f, q = 0.f;
#pragma unroll 4
            for (int c = 0; c < nch; ++c) {
                const int id = base + c * 128 + p;     // coalesced
                a += pA[id]; n += pN[id]; q += pQ[id];
            }
            A[i * 128 + p] = a; N[i * 128 + p] = n; Q[i * 128 + p] = q;
        }
        __syncthreads();

        if (t < 128) {
            const float e0 = A[t]       / (N[t]       + 0.1f);
            const float e1 = A[128 + t] / (N[128 + t] + 0.1f);
            const float e2 = A[256 + t] / (N[256 + t] + 0.1f);
            const float e3 = A[384 + t] / (N[384 + t] + 0.1f);
            int best = 0; float bv = e0;
            if (e1 < bv) { bv = e1; best = 1; }
            if (e2 < bv) { bv = e2; best = 2; }
            if (e3 < bv) { bv = e3; best = 3; }
            mask[t] = best;
            msel[t] = best;
            qsel[t] = Q[best * 128 + t];
        }
        __syncthreads();

        float loss = 0.f;
        const float wgt[4] = {0.5f, 0.25f, 0.125f, 0.0625f};
#pragma unroll
        for (int i = 0; i < 4; ++i) {
            if (t < 128) { A[t] = (msel[t] == i) ? qsel[t] : 0.f;
                           N[t] = (msel[t] == i) ? 1.f     : 0.f; }
            __syncthreads();
            for (int off = 64; off > 0; off >>= 1) {
                if (t < off) { A[t] += A[t + off]; N[t] += N[t + off]; }
                __syncthreads();
            }
            if (t == 0) {
                const float px = (float)(131072 >> (2 * i));   // kh_i*kw_i
                loss += wgt[i] * (A[0] / (N[0] * px + 0.01f));
            }
            __syncthreads();
        }
        if (t == 0) out[0] = loss;
    }

    __threadfence();
    grid.sync();

    // ---------------- Phase 3: gather + write outputs ----------------
    const int NPIX = 16 * 1024 * 1024;
    float* __restrict__ out_img = out + 1;
    float* __restrict__ lab_img = out + 1 + NPIX;
    const int gid = blockIdx.x * 256 + t;            // 0..262143

    for (int j = gid; j < 4194304; j += 262144) {    // exactly 16 iters/thread
        if (j < 4194303) {
            const int i0 = 4 * j + 3;
            f32x4 o4, l4;
#pragma unroll
            for (int p = 0; p < 4; ++p) {
                float ov, lv;
                px_val(i0 + p, pre0, gt0, pre1, gt1, pre2, gt2, pre3, gt3, mask, ov, lv);
                o4[p] = ov; l4[p] = lv;
            }
            __builtin_nontemporal_store(o4, reinterpret_cast<f32x4*>(out_img + i0));
            __builtin_nontemporal_store(l4, reinterpret_cast<f32x4*>(lab_img + i0));
        } else {
            const int edge[4] = {0, 1, 2, NPIX - 1};
#pragma unroll
            for (int p = 0; p < 4; ++p) {
                float ov, lv;
                px_val(edge[p], pre0, gt0, pre1, gt1, pre2, gt2, pre3, gt3, mask, ov, lv);
                out_img[edge[p]] = ov;
                lab_img[edge[p]] = lv;
            }
        }
    }
}

extern "C" void kernel_launch(void* const* d_in, const int* in_sizes, int n_in,
                              void* d_out, int out_size, void* d_ws, size_t ws_size,
                              hipStream_t stream) {
    // setup_inputs() dict order is INTERLEAVED: pre0, gt0, pre1, gt1, ...
    const float* pre0 = (const float*)d_in[0];
    const float* gt0  = (const float*)d_in[1];
    const float* pre1 = (const float*)d_in[2];
    const float* gt1  = (const float*)d_in[3];
    const float* pre2 = (const float*)d_in[4];
    const float* gt2  = (const float*)d_in[5];
    const float* pre3 = (const float*)d_in[6];
    const float* gt3  = (const float*)d_in[7];

    float* out = (float*)d_out;             // [0]=loss, [1..]=out_img, then lab_img
    float* pA  = (float*)d_ws;              // 5504 each, SoA planes
    float* pN  = pA + 5504;
    float* pQ  = pA + 11008;
    int*   mask = (int*)(pA + 16512);       // 128 ints

    void* args[] = { &pre0, &gt0, &pre1, &gt1, &pre2, &gt2, &pre3, &gt3,
                     &pA, &pN, &pQ, &mask, &out };
    hipLaunchCooperativeKernel((void*)k_fused, dim3(1024), dim3(256),
                               args, 0, stream);
}

// Round 7
// 367.955 us; speedup vs baseline: 1.8426x; 1.8426x over previous
//
#include <hip/hip_runtime.h>

// ---------------------------------------------------------------------------
// Geometry: B=16, H=W=1024, kh0=512 kw0=256 -> ph=2, pw=4, L=8; 128 patches.
// Pass 1 (k_err): 8192-px chunks; 8 f32x4 load-pairs hoisted per thread.
//   blocks/patch: s0=16, s1=4, s2=1, s3=1 -> bases {0,2048,2560,2688}, 2816 tot
//   (scale-3 patch is 2048 px; the px<patch_px predicate zero-fills its tail)
//   Partials SoA chunk-major: id = base_i + chunk*128 + patch (A,N,Q planes).
// Pass 2 (k_finalize): 1 block, coalesced reduce -> argmin mask + loss.
//   chunks/patch table EXPLICIT {16,4,1,1} (round-4 lesson: no >> formulas).
// Pass 3 (k_write): 8 px/thread = two 16B-aligned f32x4 NT store groups
//   (d_out+1 base => groups at i == 3 mod 4 are aligned; 8j+3 and 8j+7 ✓).
// ---------------------------------------------------------------------------

typedef float f32x4 __attribute__((ext_vector_type(4)));

__global__ __launch_bounds__(256) void k_err(
    const float* __restrict__ pre0, const float* __restrict__ gt0,
    const float* __restrict__ pre1, const float* __restrict__ gt1,
    const float* __restrict__ pre2, const float* __restrict__ gt2,
    const float* __restrict__ pre3, const float* __restrict__ gt3,
    float* __restrict__ pA, float* __restrict__ pN, float* __restrict__ pQ)
{
    const int bid = blockIdx.x;
    int scale, patch, chunk, oidx;
    const float* __restrict__ pre;
    const float* __restrict__ gt;
    if (bid < 2048)      { scale = 0; patch = bid >> 4; chunk = bid & 15;
                           oidx = chunk * 128 + patch;          pre = pre0; gt = gt0; }
    else if (bid < 2560) { scale = 1; int r = bid - 2048; patch = r >> 2; chunk = r & 3;
                           oidx = 2048 + chunk * 128 + patch;   pre = pre1; gt = gt1; }
    else if (bid < 2688) { scale = 2; patch = bid - 2560; chunk = 0;
                           oidx = 2560 + patch;                 pre = pre2; gt = gt2; }
    else                 { scale = 3; patch = bid - 2688; chunk = 0;
                           oidx = 2688 + patch;                 pre = pre3; gt = gt3; }

    const int b  = patch >> 3;
    const int l  = patch & 7;
    const int pi = l >> 2, pj = l & 3;
    const int kwshift = 8 - scale;            // kw = 256>>scale
    const int kw   = 1 << kwshift;
    const int kh   = 512 >> scale;
    const int wdim = 1024 >> scale;
    const int patch_px = 131072 >> (2 * scale);
    const int imgbase  = b * wdim * wdim;
    const int base_row = pi * kh;
    const int base_col = pj * kw;

    const int t = threadIdx.x;

    // Hoist all loads (zero-fill OOB) -> max outstanding loads, branch-free math
    f32x4 pv[8], gv[8];
#pragma unroll
    for (int s = 0; s < 8; ++s) {
        const int slot = t + s * 256;                 // 0..2047 f32x4 slots
        const int px   = chunk * 8192 + slot * 4;     // pixel index within patch
        if (px < patch_px) {                          // wave-uniform (s3 tail only)
            const int row = px >> kwshift;
            const int col = px & (kw - 1);
            const int idx = imgbase + (base_row + row) * wdim + base_col + col;
            pv[s] = *reinterpret_cast<const f32x4*>(pre + idx);
            gv[s] = *reinterpret_cast<const f32x4*>(gt + idx);
        } else {
            pv[s] = (f32x4)0.f;                       // g=0,p=0 => all terms 0
            gv[s] = (f32x4)0.f;
        }
    }

    float sumabs = 0.f, npos = 0.f, sq = 0.f;
#pragma unroll
    for (int s = 0; s < 8; ++s) {
#pragma unroll
        for (int k = 0; k < 4; ++k) {
            const float gs = gv[s][k] * 200.0f;       // gts = gt * WEIGHT
            const float d  = gs - pv[s][k];
            sq += d * d;
            if (gv[s][k] > 0.0f) { sumabs += fabsf(d); npos += 1.0f; }
        }
    }

    // wave shuffle reduce (fixed order -> deterministic), then 4-wave combine
    for (int off = 32; off > 0; off >>= 1) {
        sumabs += __shfl_down(sumabs, off);
        npos   += __shfl_down(npos,   off);
        sq     += __shfl_down(sq,     off);
    }
    __shared__ float wA[4], wN[4], wQ[4];
    const int w = t >> 6;
    if ((t & 63) == 0) { wA[w] = sumabs; wN[w] = npos; wQ[w] = sq; }
    __syncthreads();
    if (t == 0) {
        pA[oidx] = (wA[0] + wA[1]) + (wA[2] + wA[3]);
        pN[oidx] = (wN[0] + wN[1]) + (wN[2] + wN[3]);
        pQ[oidx] = (wQ[0] + wQ[1]) + (wQ[2] + wQ[3]);
    }
}

// One block, 256 threads: reduce partials per (scale,patch) coalesced,
// compute e_i, argmin (first-min tie-break), mask, loss.
__global__ __launch_bounds__(256) void k_finalize(
    const float* __restrict__ pA, const float* __restrict__ pN, const float* __restrict__ pQ,
    int* __restrict__ mask, float* __restrict__ loss_out)
{
    const int t = threadIdx.x;
    __shared__ float A[512], N[512], Q[512];   // [i*128 + p]
    __shared__ float qsel[128];
    __shared__ int   msel[128];

    const int p  = t & 127;
    const int i0 = (t < 128) ? 0 : 1;
#pragma unroll
    for (int k = 0; k < 2; ++k) {
        const int i    = i0 + 2 * k;
        const int base = (i == 0) ? 0 : (i == 1) ? 2048 : (i == 2) ? 2560 : 2688;
        const int nch  = (i == 0) ? 16 : (i == 1) ? 4 : 1;   // EXPLICIT table
        float a = 0.f, n = 0.f, q = 0.f;
#pragma unroll 4
        for (int c = 0; c < nch; ++c) {
            const int id = base + c * 128 + p;     // lanes p consecutive: coalesced
            a += pA[id]; n += pN[id]; q += pQ[id];
        }
        A[i * 128 + p] = a; N[i * 128 + p] = n; Q[i * 128 + p] = q;
    }
    __syncthreads();

    if (t < 128) {
        const float e0 = A[t]       / (N[t]       + 0.1f);
        const float e1 = A[128 + t] / (N[128 + t] + 0.1f);
        const float e2 = A[256 + t] / (N[256 + t] + 0.1f);
        const float e3 = A[384 + t] / (N[384 + t] + 0.1f);
        int best = 0; float bv = e0;
        if (e1 < bv) { bv = e1; best = 1; }
        if (e2 < bv) { bv = e2; best = 2; }
        if (e3 < bv) { bv = e3; best = 3; }
        mask[t] = best;
        msel[t] = best;
        qsel[t] = Q[best * 128 + t];
    }
    __syncthreads();

    float loss = 0.f;
    const float wgt[4] = {0.5f, 0.25f, 0.125f, 0.0625f};
#pragma unroll
    for (int i = 0; i < 4; ++i) {
        if (t < 128) { A[t] = (msel[t] == i) ? qsel[t] : 0.f;
                       N[t] = (msel[t] == i) ? 1.f     : 0.f; }
        __syncthreads();
        for (int off = 64; off > 0; off >>= 1) {
            if (t < off) { A[t] += A[t + off]; N[t] += N[t + off]; }
            __syncthreads();
        }
        if (t == 0) {
            const float px = (float)(131072 >> (2 * i));   // kh_i*kw_i
            loss += wgt[i] * (A[0] / (N[0] * px + 0.01f));
        }
        __syncthreads();
    }
    if (t == 0) loss_out[0] = loss;
}

__device__ __forceinline__ void px_val(
    int i,
    const float* __restrict__ pre0, const float* __restrict__ gt0,
    const float* __restrict__ pre1, const float* __restrict__ gt1,
    const float* __restrict__ pre2, const float* __restrict__ gt2,
    const float* __restrict__ pre3, const float* __restrict__ gt3,
    const int* __restrict__ mask, float& ov, float& lv)
{
    const int b = i >> 20;
    const int y = (i >> 10) & 1023;
    const int x = i & 1023;
    const int pi = y >> 9, pj = x >> 8;
    const int r  = y & 511, c = x & 255;
    const int m  = mask[(b << 3) + (pi << 2) + pj];
    const int kh = 512 >> m, kw = 256 >> m;
    const unsigned rr = (unsigned)(r - ((512 - kh) >> 1));
    const unsigned cc = (unsigned)(c - ((256 - kw) >> 1));
    if (rr < (unsigned)kh && cc < (unsigned)kw) {
        const int wdim = 1024 >> m;
        const float* __restrict__ pre = (m == 0) ? pre0 : (m == 1) ? pre1 : (m == 2) ? pre2 : pre3;
        const float* __restrict__ gt  = (m == 0) ? gt0  : (m == 1) ? gt1  : (m == 2) ? gt2  : gt3;
        const int idx = b * wdim * wdim + (pi * kh + (int)rr) * wdim + (pj * kw + (int)cc);
        ov = pre[idx] * (1.0f / 200.0f);
        lv = gt[idx];
    } else {
        ov = 0.001f;       // 0.2 / WEIGHT
        lv = 0.001f;
    }
}

// 8 px/thread: two aligned f32x4 NT-store groups (i0=8j+3 and 8j+7, both
// ≡3 mod 4 => 16B-aligned at d_out+1). Thread j==2097151 mops up the 8
// leftover pixels {0,1,2, 16777211..16777215}.
__global__ __launch_bounds__(256) void k_write(
    const float* __restrict__ pre0, const float* __restrict__ gt0,
    const float* __restrict__ pre1, const float* __restrict__ gt1,
    const float* __restrict__ pre2, const float* __restrict__ gt2,
    const float* __restrict__ pre3, const float* __restrict__ gt3,
    const int* __restrict__ mask, float* __restrict__ out)
{
    const int NPIX = 16 * 1024 * 1024;
    const int j = blockIdx.x * 256 + threadIdx.x;    // < 2,097,152
    float* __restrict__ out_img = out + 1;
    float* __restrict__ lab_img = out + 1 + NPIX;

    if (j < 2097151) {
        const int i0 = 8 * j + 3;
        f32x4 o4a, l4a, o4b, l4b;
#pragma unroll
        for (int p = 0; p < 4; ++p) {
            float ov, lv;
            px_val(i0 + p, pre0, gt0, pre1, gt1, pre2, gt2, pre3, gt3, mask, ov, lv);
            o4a[p] = ov; l4a[p] = lv;
        }
#pragma unroll
        for (int p = 0; p < 4; ++p) {
            float ov, lv;
            px_val(i0 + 4 + p, pre0, gt0, pre1, gt1, pre2, gt2, pre3, gt3, mask, ov, lv);
            o4b[p] = ov; l4b[p] = lv;
        }
        __builtin_nontemporal_store(o4a, reinterpret_cast<f32x4*>(out_img + i0));
        __builtin_nontemporal_store(o4b, reinterpret_cast<f32x4*>(out_img + i0 + 4));
        __builtin_nontemporal_store(l4a, reinterpret_cast<f32x4*>(lab_img + i0));
        __builtin_nontemporal_store(l4b, reinterpret_cast<f32x4*>(lab_img + i0 + 4));
    } else {
        const int edge[8] = {0, 1, 2, NPIX - 5, NPIX - 4, NPIX - 3, NPIX - 2, NPIX - 1};
#pragma unroll
        for (int p = 0; p < 8; ++p) {
            float ov, lv;
            px_val(edge[p], pre0, gt0, pre1, gt1, pre2, gt2, pre3, gt3, mask, ov, lv);
            out_img[edge[p]] = ov;
            lab_img[edge[p]] = lv;
        }
    }
}

extern "C" void kernel_launch(void* const* d_in, const int* in_sizes, int n_in,
                              void* d_out, int out_size, void* d_ws, size_t ws_size,
                              hipStream_t stream) {
    // setup_inputs() dict order is INTERLEAVED: pre0, gt0, pre1, gt1, ...
    const float* pre0 = (const float*)d_in[0];
    const float* gt0  = (const float*)d_in[1];
    const float* pre1 = (const float*)d_in[2];
    const float* gt1  = (const float*)d_in[3];
    const float* pre2 = (const float*)d_in[4];
    const float* gt2  = (const float*)d_in[5];
    const float* pre3 = (const float*)d_in[6];
    const float* gt3  = (const float*)d_in[7];

    float* out = (float*)d_out;             // [0]=loss, [1..]=out_img, then lab_img
    float* pA  = (float*)d_ws;              // 2816 each, SoA planes
    float* pN  = pA + 2816;
    float* pQ  = pA + 5632;
    int*   mask = (int*)(pA + 8448);        // 128 ints

    k_err<<<2816, 256, 0, stream>>>(pre0, gt0, pre1, gt1, pre2, gt2, pre3, gt3, pA, pN, pQ);
    k_finalize<<<1, 256, 0, stream>>>(pA, pN, pQ, mask, out);
    k_write<<<8192, 256, 0, stream>>>(pre0, gt0, pre1, gt1, pre2, gt2, pre3, gt3, mask, out);
}